// Round 8
// baseline (232.706 us; speedup 1.0000x reference)
//
#include <hip/hip_runtime.h>
#include <hip/hip_bf16.h>

typedef __attribute__((ext_vector_type(8))) __bf16 bf16x8;
typedef __attribute__((ext_vector_type(4))) float f32x4;

#define NB 32768
#define HDIM 512
#define KDIM 1024

struct WPtrs { const float* wi[4]; const float* wh[4]; };
struct BPtrs { const float* bi[4]; const float* bh[4]; };

__device__ __forceinline__ float fsigmoid(float x) {
  return 1.0f / (1.0f + __expf(-x));
}
__device__ __forceinline__ float ftanh(float x) {
  return 2.0f / (1.0f + __expf(-2.0f * x)) - 1.0f;
}
__device__ __forceinline__ bf16x8 pack8(float4 a, float4 b) {
  bf16x8 r;
  r[0] = (__bf16)a.x; r[1] = (__bf16)a.y; r[2] = (__bf16)a.z; r[3] = (__bf16)a.w;
  r[4] = (__bf16)b.x; r[5] = (__bf16)b.y; r[6] = (__bf16)b.z; r[7] = (__bf16)b.w;
  return r;
}
__device__ __forceinline__ void gll16(const void* g, void* l) {
  __builtin_amdgcn_global_load_lds(
      (const __attribute__((address_space(1))) void*)g,
      (__attribute__((address_space(3))) void*)l, 16, 0, 0);
}
#define MFMA16(A, B, C) \
  C = __builtin_amdgcn_mfma_f32_16x16x32_bf16(A, B, C, 0, 0, 0)
#define SBAR() __builtin_amdgcn_s_barrier()
#define SCHED0() __builtin_amdgcn_sched_barrier(0)
#define LGKM(n) asm volatile("s_waitcnt lgkmcnt(" #n ")" ::: "memory")

// ====================== prep ======================
__global__ void pack_bias_kernel(BPtrs p, float* __restrict__ bias) {
  int idx = blockIdx.x * 256 + threadIdx.x;  // 0..2047
  int g = idx >> 9, np = idx & 511;
  bias[idx] = p.bi[g][np] + p.bh[g][np];
}

// A = [x | h] -> bf16 [32768][1024]
__global__ void conv_a_kernel(const float* __restrict__ x,
                              const float* __restrict__ h,
                              __bf16* __restrict__ Abf) {
  const size_t N8 = (size_t)NB * KDIM / 8;
  for (size_t i = (size_t)blockIdx.x * blockDim.x + threadIdx.x; i < N8;
       i += (size_t)gridDim.x * blockDim.x) {
    size_t e = i * 8;
    int k = (int)(e & (KDIM - 1));
    size_t r = e >> 10;
    const float* s = (k < 512) ? (x + r * 512 + k) : (h + r * 512 + (k - 512));
    float4 v0 = *(const float4*)s;
    float4 v1 = *(const float4*)(s + 4);
    *(bf16x8*)(Abf + e) = pack8(v0, v1);
  }
}

// Wt[p][k], p(np,g) = (np>>4)*64 + g*16 + (np&15)
// -> each 64-p group = all 4 gates of one 16-col np group (wave N-span = 64).
__global__ void pack_w3_kernel(WPtrs p, __bf16* __restrict__ Wt) {
  __shared__ float tile[64][65];
  const int kt = blockIdx.x;  // 16 k-tiles of 64
  const int nt = blockIdx.y;  // 8 np-tiles of 64
  const int g = blockIdx.z;   // gate
  const int k0 = kt * 64, n0 = nt * 64;
  const float* src = (k0 < 512) ? p.wi[g] : p.wh[g];
  const int k0l = (k0 < 512) ? k0 : (k0 - 512);
  const int rr = threadIdx.x >> 6;
  const int cc = threadIdx.x & 63;
#pragma unroll
  for (int pp = 0; pp < 16; ++pp) {
    int kk = pp * 4 + rr;
    tile[kk][cc] = src[(size_t)(k0l + kk) * 512 + (n0 + cc)];
  }
  __syncthreads();
#pragma unroll
  for (int pp = 0; pp < 16; ++pp) {
    int nn = pp * 4 + rr;
    int np = n0 + nn;
    int prow = ((np >> 4) << 6) + (g << 4) + (np & 15);
    Wt[(size_t)prow * KDIM + (k0 + cc)] = (__bf16)tile[cc][nn];
  }
}

// ========== main: 128x128 tile, BK=64, dbuf 64KiB, 2 blocks/CU ==========
// Occupancy experiment: 2 independent 256-thread blocks per CU (64KiB LDS
// each) -> two barrier domains anti-phase on the same SIMDs; one block's
// MFMA covers the other's lgkm/vmcnt/barrier exposure (m114/m97 mechanism).
// Per-tile schedule = r5's proven staircase; drain = m97's vmcnt(0)+SBAR.
// Hazards (dbuf-2): reads of tile t (buf t&1) retire at the lgkm(0) before
// the last MFMA group, before t's terminal SBAR; stages in t write buf
// (t+1)&1 whose readers retired before t-1's terminal SBAR; readers of
// stage(t+1) run after t's vmcnt(0)+SBAR. All safe with ONE barrier/tile.
__global__ __launch_bounds__(256, 2) void lstm_gemm7(
    const __bf16* __restrict__ Abf, const __bf16* __restrict__ Wt,
    const float* __restrict__ cin, const float* __restrict__ bias,
    float* __restrict__ out) {
  __shared__ alignas(16) char lds[65536];
  const int tid = threadIdx.x;
  const int wid = tid >> 6;                // 0..3
  const int wm = wid >> 1, wn = wid & 1;   // 2M x 2N waves, wave = 64x64
  const int lane = tid & 63;
  const int fc = lane & 15, fg = lane >> 4;

  const int bn = blockIdx.x & 15;   // 16 B-panels of 128 cols (32 np x 4 gates)
  const int bmg = blockIdx.x >> 4;  // 0..31, each covers 8 x 128 rows

  const __bf16* Bsrc = Wt + (size_t)(bn * 128) * KDIM;

  const int r0 = tid >> 3;                     // 0..31 staging row
  const int ssl = ((tid & 7) ^ (r0 & 7)) * 8;  // inverse-swizzled k-slot
  const uint32_t ldst0 = (uint32_t)wid * 1024;

  f32x4 acc[4][4];
#pragma unroll
  for (int m = 0; m < 4; ++m)
#pragma unroll
    for (int n = 0; n < 4; ++n) acc[m][n] = (f32x4){0.f, 0.f, 0.f, 0.f};

  bf16x8 a0[4], b0[4], a1[4], b1[4];

  auto stA = [&](int t) {
    if (t < 128) {
      const int rt = (bmg << 3) + (t >> 4);
      const __bf16* s =
          Abf + (size_t)(rt * 128 + r0) * KDIM + (t & 15) * 64 + ssl;
      uint32_t lb = (uint32_t)(t & 1) * 32768 + ldst0;
      gll16(s, (void*)&lds[lb]);
      gll16(s + (size_t)32 * KDIM, (void*)&lds[lb + 4096]);
      gll16(s + (size_t)64 * KDIM, (void*)&lds[lb + 8192]);
      gll16(s + (size_t)96 * KDIM, (void*)&lds[lb + 12288]);
    }
  };
  auto stB = [&](int t) {
    if (t < 128) {
      const __bf16* s = Bsrc + (size_t)r0 * KDIM + (t & 15) * 64 + ssl;
      uint32_t lb = (uint32_t)(t & 1) * 32768 + 16384 + ldst0;
      gll16(s, (void*)&lds[lb]);
      gll16(s + (size_t)32 * KDIM, (void*)&lds[lb + 4096]);
      gll16(s + (size_t)64 * KDIM, (void*)&lds[lb + 8192]);
      gll16(s + (size_t)96 * KDIM, (void*)&lds[lb + 12288]);
    }
  };
  auto ldA = [&](int cb, int mq, int ks) -> bf16x8 {
    int row = wm * 64 + mq * 16 + fc;
    uint32_t off = (uint32_t)cb * 32768 + (uint32_t)row * 128 +
                   (uint32_t)(((ks * 4 + fg) ^ (row & 7)) << 4);
    return *(const bf16x8*)&lds[off];
  };
  auto ldB = [&](int cb, int nq, int ks) -> bf16x8 {
    int row = wn * 64 + nq * 16 + fc;
    uint32_t off = (uint32_t)cb * 32768 + 16384 + (uint32_t)row * 128 +
                   (uint32_t)(((ks * 4 + fg) ^ (row & 7)) << 4);
    return *(const bf16x8*)&lds[off];
  };

  // hoisted epilogue constants
  const int np = bn * 32 + wn * 16 + fc;
  const float bi = bias[np];
  const float bf_ = bias[512 + np];
  const float bg = bias[1024 + np];
  const float bo = bias[1536 + np];
  const size_t couts = (size_t)NB * HDIM;

  // prologue
  stA(0);
  stB(0);
  asm volatile("s_waitcnt vmcnt(0)" ::: "memory");
  SBAR();

#pragma unroll 2
  for (int t = 0; t < 128; ++t) {
    const int cb = t & 1;
    // issue all 16 reads in-order: B@k0(1-4), A@k0(5-8), B@k1(9-12), A@k1(13-16)
    b0[0] = ldB(cb, 0, 0); b0[1] = ldB(cb, 1, 0);
    b0[2] = ldB(cb, 2, 0); b0[3] = ldB(cb, 3, 0);
    a0[0] = ldA(cb, 0, 0); a0[1] = ldA(cb, 1, 0);
    a0[2] = ldA(cb, 2, 0); a0[3] = ldA(cb, 3, 0);
    b1[0] = ldB(cb, 0, 1); b1[1] = ldB(cb, 1, 1);
    b1[2] = ldB(cb, 2, 1); b1[3] = ldB(cb, 3, 1);
    a1[0] = ldA(cb, 0, 1); a1[1] = ldA(cb, 1, 1);
    a1[2] = ldA(cb, 2, 1); a1[3] = ldA(cb, 3, 1);
    // ---- k0 staircase: group mq needs reads 1..(5+mq) ----
    LGKM(11); SCHED0();
    __builtin_amdgcn_s_setprio(1);
    MFMA16(a0[0], b0[0], acc[0][0]); MFMA16(a0[0], b0[1], acc[0][1]);
    MFMA16(a0[0], b0[2], acc[0][2]); MFMA16(a0[0], b0[3], acc[0][3]);
    __builtin_amdgcn_s_setprio(0);
    LGKM(10); SCHED0();
    __builtin_amdgcn_s_setprio(1);
    MFMA16(a0[1], b0[0], acc[1][0]); MFMA16(a0[1], b0[1], acc[1][1]);
    MFMA16(a0[1], b0[2], acc[1][2]); MFMA16(a0[1], b0[3], acc[1][3]);
    __builtin_amdgcn_s_setprio(0);
    stA(t + 1);  // 4 gll16 (vmcnt only, lgkm untouched)
    LGKM(9); SCHED0();
    __builtin_amdgcn_s_setprio(1);
    MFMA16(a0[2], b0[0], acc[2][0]); MFMA16(a0[2], b0[1], acc[2][1]);
    MFMA16(a0[2], b0[2], acc[2][2]); MFMA16(a0[2], b0[3], acc[2][3]);
    __builtin_amdgcn_s_setprio(0);
    LGKM(8); SCHED0();
    __builtin_amdgcn_s_setprio(1);
    MFMA16(a0[3], b0[0], acc[3][0]); MFMA16(a0[3], b0[1], acc[3][1]);
    MFMA16(a0[3], b0[2], acc[3][2]); MFMA16(a0[3], b0[3], acc[3][3]);
    __builtin_amdgcn_s_setprio(0);
    stB(t + 1);
    // ---- k1 staircase: group mq needs reads through 13+mq ----
    LGKM(3); SCHED0();
    __builtin_amdgcn_s_setprio(1);
    MFMA16(a1[0], b1[0], acc[0][0]); MFMA16(a1[0], b1[1], acc[0][1]);
    MFMA16(a1[0], b1[2], acc[0][2]); MFMA16(a1[0], b1[3], acc[0][3]);
    __builtin_amdgcn_s_setprio(0);
    LGKM(2); SCHED0();
    __builtin_amdgcn_s_setprio(1);
    MFMA16(a1[1], b1[0], acc[1][0]); MFMA16(a1[1], b1[1], acc[1][1]);
    MFMA16(a1[1], b1[2], acc[1][2]); MFMA16(a1[1], b1[3], acc[1][3]);
    __builtin_amdgcn_s_setprio(0);
    LGKM(1); SCHED0();
    __builtin_amdgcn_s_setprio(1);
    MFMA16(a1[2], b1[0], acc[2][0]); MFMA16(a1[2], b1[1], acc[2][1]);
    MFMA16(a1[2], b1[2], acc[2][2]); MFMA16(a1[2], b1[3], acc[2][3]);
    __builtin_amdgcn_s_setprio(0);
    LGKM(0); SCHED0();
    __builtin_amdgcn_s_setprio(1);
    MFMA16(a1[3], b1[0], acc[3][0]); MFMA16(a1[3], b1[1], acc[3][1]);
    MFMA16(a1[3], b1[2], acc[3][2]); MFMA16(a1[3], b1[3], acc[3][3]);
    __builtin_amdgcn_s_setprio(0);
    // ---- drain stage(t+1), single barrier (covered by sibling block) ----
    asm volatile("s_waitcnt vmcnt(0)" ::: "memory");
    SBAR();

    // ---- inline LSTM epilogue at group end (regs+global only) ----
    if ((t & 15) == 15) {
      const int rt = (bmg << 3) + (t >> 4);
#pragma unroll
      for (int mf = 0; mf < 4; ++mf) {
        const int grow0 = rt * 128 + wm * 64 + mf * 16 + fg * 4;
#pragma unroll
        for (int j = 0; j < 4; ++j) {
          const size_t off = (size_t)(grow0 + j) * HDIM + np;
          float i_ = fsigmoid(acc[mf][0][j] + bi);
          float f_ = fsigmoid(acc[mf][1][j] + bf_);
          float g_ = fsigmoid(acc[mf][2][j] + bg);
          float o_ = fsigmoid(acc[mf][3][j] + bo);
          float cp = f_ * cin[off] + i_ * g_;
          out[off] = o_ * ftanh(cp);
          out[couts + off] = cp;
        }
#pragma unroll
        for (int n = 0; n < 4; ++n) acc[mf][n] = (f32x4){0.f, 0.f, 0.f, 0.f};
      }
    }
  }
}

// ====================== launch ======================
extern "C" void kernel_launch(void* const* d_in, const int* in_sizes, int n_in,
                              void* d_out, int out_size, void* d_ws,
                              size_t ws_size, hipStream_t stream) {
  const float* xin = (const float*)d_in[0];
  const float* hin = (const float*)d_in[1];
  const float* cin = (const float*)d_in[2];
  WPtrs wp;
  wp.wi[0] = (const float*)d_in[3];
  wp.wi[1] = (const float*)d_in[7];
  wp.wi[2] = (const float*)d_in[11];
  wp.wi[3] = (const float*)d_in[15];
  wp.wh[0] = (const float*)d_in[4];
  wp.wh[1] = (const float*)d_in[8];
  wp.wh[2] = (const float*)d_in[12];
  wp.wh[3] = (const float*)d_in[16];
  BPtrs bp;
  bp.bi[0] = (const float*)d_in[5];
  bp.bi[1] = (const float*)d_in[9];
  bp.bi[2] = (const float*)d_in[13];
  bp.bi[3] = (const float*)d_in[17];
  bp.bh[0] = (const float*)d_in[6];
  bp.bh[1] = (const float*)d_in[10];
  bp.bh[2] = (const float*)d_in[14];
  bp.bh[3] = (const float*)d_in[18];

  const size_t needA = (size_t)NB * KDIM * 2;    // 64 MiB
  const size_t needW = (size_t)2048 * KDIM * 2;  // 4 MiB

  __bf16* Abf = (__bf16*)d_ws;
  __bf16* Wt = (__bf16*)((char*)d_ws + needA);
  float* bias = (float*)((char*)d_ws + needA + needW);

  conv_a_kernel<<<2048, 256, 0, stream>>>(xin, hin, Abf);
  pack_w3_kernel<<<dim3(16, 8, 4), 256, 0, stream>>>(wp, Wt);
  pack_bias_kernel<<<8, 256, 0, stream>>>(bp, bias);
  lstm_gemm7<<<512, 256, 0, stream>>>(Abf, Wt, cin, bias, (float*)d_out);
}